// Round 3
// baseline (381.683 us; speedup 1.0000x reference)
//
#include <hip/hip_runtime.h>

#define NN 16384   // total nodes (4*64*64)
#define CC 48      // channels
#define SPL 4      // j-stream splits (part layout unchanged)

typedef __attribute__((ext_vector_type(8))) short bf16x8;
typedef __attribute__((ext_vector_type(4))) float f32x4;

__device__ __forceinline__ unsigned short f2bf(float f) {
  unsigned u = __float_as_uint(f);
  unsigned r = ((u >> 16) & 1u) + 0x7fffu;   // RNE
  return (unsigned short)((u + r) >> 16);
}
__device__ __forceinline__ float bf2f(unsigned short h) {
  return __uint_as_float(((unsigned)h) << 16);
}

// Parallel sorted-insert (ascending 9-queue), med3-identity form: 17 ops, dep depth 2.
// f64 version: used ONLY in the short final phase (~10 inserts) on packed
// positive-denormal keys (f64 bit order == u64 order for positive values;
// f64 denormals are always IEEE on CDNA — never flushed).
__device__ __forceinline__ void ins9(double c, double q[9]) {
  double m1 = fmin(q[1], c), m2 = fmin(q[2], c), m3 = fmin(q[3], c),
         m4 = fmin(q[4], c), m5 = fmin(q[5], c), m6 = fmin(q[6], c),
         m7 = fmin(q[7], c), m8 = fmin(q[8], c);
  double n0 = fmin(q[0], c);
  double n1 = fmax(q[0], m1), n2 = fmax(q[1], m2), n3 = fmax(q[2], m3),
         n4 = fmax(q[3], m4), n5 = fmax(q[4], m5), n6 = fmax(q[5], m6),
         n7 = fmax(q[6], m7), n8 = fmax(q[7], m8);
  q[0] = n0; q[1] = n1; q[2] = n2; q[3] = n3; q[4] = n4;
  q[5] = n5; q[6] = n6; q[7] = n7; q[8] = n8;
}

// u32 version for the hot loop: v_min_u32/v_max_u32 are full-rate (2 cyc)
// vs f64 min/max on the half/quarter-rate DP pipe (~6-8 cyc measured via
// R0 counter math: 570 VALU-cyc/tile with 68 f64 ops/tile).
__device__ __forceinline__ void ins9u(unsigned c, unsigned q[9]) {
  unsigned m1 = min(q[1], c), m2 = min(q[2], c), m3 = min(q[3], c),
           m4 = min(q[4], c), m5 = min(q[5], c), m6 = min(q[6], c),
           m7 = min(q[7], c), m8 = min(q[8], c);
  unsigned n0 = min(q[0], c);
  unsigned n1 = max(q[0], m1), n2 = max(q[1], m2), n3 = max(q[2], m3),
           n4 = max(q[3], m4), n5 = max(q[4], m5), n6 = max(q[5], m6),
           n7 = max(q[6], m7), n8 = max(q[8 - 1], m8);
  q[0] = n0; q[1] = n1; q[2] = n2; q[3] = n3; q[4] = n4;
  q[5] = n5; q[6] = n6; q[7] = n7; q[8] = n8;
}

// ---------- kernel 1: [B,C,H,W] -> xg[N][52] fp32, xh/xl[N][64] bf16 split, sqv[N] ----------
__global__ __launch_bounds__(256) void prep_kernel(const float* __restrict__ x,
                                                   float* __restrict__ xg,
                                                   unsigned short* __restrict__ xh,
                                                   unsigned short* __restrict__ xl,
                                                   float* __restrict__ sqv,
                                                   int* __restrict__ deg) {
  __shared__ float tile[48][65];   // +1 pad
  __shared__ float sqcol[64];
  int tid = threadIdx.x;
  int b   = blockIdx.x >> 6;          // batch image 0..3
  int hw0 = (blockIdx.x & 63) << 6;   // 64-wide hw tile
  if (tid < 64) deg[blockIdx.x * 64 + tid] = 0;
#pragma unroll
  for (int p = 0; p < 12; ++p) {
    int it = tid + p * 256;
    int r = it >> 6, col = it & 63;
    tile[r][col] = x[(b * 48 + r) * 4096 + hw0 + col];
  }
  __syncthreads();
  if (tid < 64) {
    float s = 0.f;
#pragma unroll
    for (int r = 0; r < 48; ++r) { float v = tile[r][tid]; s += v * v; }
    sqcol[tid] = s;
    int node = b * 4096 + hw0 + tid;
    sqv[node] = (node == NN - 1) ? __builtin_inff() : s;
  }
  __syncthreads();
  float4* xg4 = (float4*)xg;
#pragma unroll
  for (int p = 0; p < 4; ++p) {
    int it = tid + p * 256;
    if (it < 832) {
      int col = it / 13;
      int q   = it - col * 13;
      float4 v;
      if (q < 12) {
        v.x = tile[q * 4 + 0][col]; v.y = tile[q * 4 + 1][col];
        v.z = tile[q * 4 + 2][col]; v.w = tile[q * 4 + 3][col];
      } else {
        v.x = sqcol[col]; v.y = 0.f; v.z = 0.f; v.w = 0.f;
      }
      xg4[(b * 4096 + hw0 + col) * 13 + q] = v;
    }
  }
  // bf16 hi/lo split, channels padded 48..63 with zeros
#pragma unroll
  for (int p = 0; p < 16; ++p) {
    int it = tid + p * 256;          // 4096 = 64 nodes x 64 ch
    int col = it >> 6, ch = it & 63;
    float v = (ch < 48) ? tile[ch][col] : 0.f;
    unsigned short h = f2bf(v);
    unsigned short l = f2bf(v - bf2f(h));
    size_t o = (size_t)(b * 4096 + hw0 + col) * 64 + ch;
    xh[o] = h;
    xl[o] = l;
  }
}

// ---------- kernel 2: MFMA distance + two-pass exact top-9 ----------
// R2 post-mortem: occupancy 41->56% bought nothing (R0 150.8us vs R2 159.5us,
// same hot-loop work) => VALU-ISSUE-bound, and ~75% of hot-loop issue was the
// 68 f64 fmin/fmax per tile (DP pipe half/quarter rate). Redesign:
//   pass 1: queue holds k32 VALUES only (u32 min/max, full-rate). 68x2cyc.
//   pass 2: re-stream tiles (MFMA recompute is bit-exact; matrix pipe was 93%
//           idle; loads L2-hot), push candidates with k32 <= qv[8] as packed
//           (k32<<14)|j u64 onto a per-lane LDS stack (~9/lane, exec-masked).
//   final:  ~10 ins9 inserts of stack entries viewed as positive-denormal f64
//           (bit order == u64 order; f64 denorms always IEEE on CDNA). The f64
//           bit pattern IS the packed u64 key -> old decode epilogue deleted.
// Ties at the boundary value are exact via the full (k32,j) key; stack depth 16
// can only overflow under >=8-way exact f32 ties (never for this input).
// Merge staging / part layout / merge_kernel semantics unchanged.
__global__ __launch_bounds__(256, 4) void knn_kernel(const unsigned short* __restrict__ xh,
                                                     const unsigned short* __restrict__ xl,
                                                     const float* __restrict__ sqv,
                                                     unsigned long long* __restrict__ part) {
  // per-wave 8KB region: stack [16 slots][64 lanes] u64; later overlaid by
  // fin [64 lanes][9] u64 (stack is dead before fin writes; cross-wave reads
  // of fin happen only after __syncthreads, when that wave's stack is dead).
  __shared__ unsigned long long lds[4 * 16 * 64];   // 32 KB
  int tid = threadIdx.x, wv = tid >> 6, lane = tid & 63;
  int qt = blockIdx.x & 1023, sp = blockIdx.x >> 10;
  int col = lane & 15, quad = lane >> 4;
  int batch = qt >> 8;
  int js = batch * 4096 + sp * 1024;
  int cbase = js + wv * 256;          // this wave's candidate quarter
  unsigned long long* wstk = lds + wv * 1024;   // [s*64 + lane]
  unsigned long long* wfin = lds + wv * 1024;   // [l*9 + k] overlay

  // resident B-frags (queries)
  int qnode = qt * 16 + col;
  bf16x8 bh0 = *(const bf16x8*)(xh + (size_t)qnode * 64 + quad * 8);
  bf16x8 bh1 = *(const bf16x8*)(xh + (size_t)qnode * 64 + 32 + quad * 8);
  bf16x8 bl0 = *(const bf16x8*)(xl + (size_t)qnode * 64 + quad * 8);
  bf16x8 bl1 = *(const bf16x8*)(xl + (size_t)qnode * 64 + 32 + quad * 8);

  unsigned qv[9];
#pragma unroll
  for (int k = 0; k < 9; ++k) qv[k] = 0xFFFFFFFFu;

  // ---- pass 1: u32 value-only queue ----
  {
    const unsigned short* pah = xh + ((size_t)(cbase + col) * 64 + quad * 8);
    const unsigned short* pal = xl + ((size_t)(cbase + col) * 64 + quad * 8);
    const float*          psq = sqv + (cbase + quad * 4);
    bf16x8 nh0 = *(const bf16x8*)(pah);
    bf16x8 nh1 = *(const bf16x8*)(pah + 32);
    bf16x8 nl0 = *(const bf16x8*)(pal);
    bf16x8 nl1 = *(const bf16x8*)(pal + 32);
    float4 nsq = *(const float4*)(psq);

    for (int t = 0; t < 16; ++t) {
      bf16x8 ch0 = nh0, ch1 = nh1, cl0 = nl0, cl1 = nl1;
      float4 csq = nsq;
      int adv = (t < 15) ? 1024 : 0;       // 16 nodes * 64 ch
      pah += adv; pal += adv;
      nh0 = *(const bf16x8*)(pah);
      nh1 = *(const bf16x8*)(pah + 32);
      nl0 = *(const bf16x8*)(pal);
      nl1 = *(const bf16x8*)(pal + 32);
      psq += (t < 15) ? 16 : 0;
      nsq = *(const float4*)(psq);

      f32x4 acc = {0.f, 0.f, 0.f, 0.f};
      acc = __builtin_amdgcn_mfma_f32_16x16x32_bf16(ch0, bh0, acc, 0, 0, 0);
      acc = __builtin_amdgcn_mfma_f32_16x16x32_bf16(ch1, bh1, acc, 0, 0, 0);
      acc = __builtin_amdgcn_mfma_f32_16x16x32_bf16(ch0, bl0, acc, 0, 0, 0);
      acc = __builtin_amdgcn_mfma_f32_16x16x32_bf16(ch1, bl1, acc, 0, 0, 0);
      acc = __builtin_amdgcn_mfma_f32_16x16x32_bf16(cl0, bh0, acc, 0, 0, 0);
      acc = __builtin_amdgcn_mfma_f32_16x16x32_bf16(cl1, bh1, acc, 0, 0, 0);

      float sq4[4] = {csq.x, csq.y, csq.z, csq.w};
#pragma unroll
      for (int reg = 0; reg < 4; ++reg) {
        float d = fmaf(-2.f, acc[reg], sq4[reg]);
        unsigned k32 = __float_as_uint(d);
        k32 = ((int)k32 >= 0) ? (k32 | 0x80000000u) : ~k32;   // sortable map
        ins9u(k32, qv);
      }
    }
  }
  unsigned thresh = qv[8];   // exact 9th-smallest k32 value for this lane

  // ---- pass 2: recompute (bit-exact) + push matches to LDS stack ----
  int cnt = 0;
  int jb = cbase + quad * 4;          // j = jb + t*16 + reg
  {
    const unsigned short* pah = xh + ((size_t)(cbase + col) * 64 + quad * 8);
    const unsigned short* pal = xl + ((size_t)(cbase + col) * 64 + quad * 8);
    const float*          psq = sqv + (cbase + quad * 4);
    for (int t = 0; t < 16; ++t) {
      bf16x8 ch0 = *(const bf16x8*)(pah);
      bf16x8 ch1 = *(const bf16x8*)(pah + 32);
      bf16x8 cl0 = *(const bf16x8*)(pal);
      bf16x8 cl1 = *(const bf16x8*)(pal + 32);
      float4 csq = *(const float4*)(psq);
      pah += 1024; pal += 1024; psq += 16;

      f32x4 acc = {0.f, 0.f, 0.f, 0.f};
      acc = __builtin_amdgcn_mfma_f32_16x16x32_bf16(ch0, bh0, acc, 0, 0, 0);
      acc = __builtin_amdgcn_mfma_f32_16x16x32_bf16(ch1, bh1, acc, 0, 0, 0);
      acc = __builtin_amdgcn_mfma_f32_16x16x32_bf16(ch0, bl0, acc, 0, 0, 0);
      acc = __builtin_amdgcn_mfma_f32_16x16x32_bf16(ch1, bl1, acc, 0, 0, 0);
      acc = __builtin_amdgcn_mfma_f32_16x16x32_bf16(cl0, bh0, acc, 0, 0, 0);
      acc = __builtin_amdgcn_mfma_f32_16x16x32_bf16(cl1, bh1, acc, 0, 0, 0);

      float sq4[4] = {csq.x, csq.y, csq.z, csq.w};
#pragma unroll
      for (int reg = 0; reg < 4; ++reg) {
        float d = fmaf(-2.f, acc[reg], sq4[reg]);
        unsigned k32 = __float_as_uint(d);
        k32 = ((int)k32 >= 0) ? (k32 | 0x80000000u) : ~k32;
        if (k32 <= thresh) {
          int slot = min(cnt, 15);           // clamp: no cross-lane corruption
          wstk[slot * 64 + lane] =
              ((unsigned long long)k32 << 14) | (unsigned)(jb + t * 16 + reg);
          cnt++;
        }
      }
    }
  }

  // ---- final: exact (k32,j)-ordered top-9 from ~9-10 stack entries ----
  double q9d[9];
#pragma unroll
  for (int k = 0; k < 9; ++k) q9d[k] = __builtin_inf();
  for (int s = 0; s < 16; ++s) {
    if (__all(s >= cnt)) break;              // iterations = wave-max(cnt) ~ 9-10
    unsigned long long v = wstk[s * 64 + lane];
    double key = (s < cnt) ? __longlong_as_double((long long)v) : __builtin_inf();
    ins9(key, q9d);
  }
  // bit pattern IS the packed (k32<<14)|j key (positive denormal)
  unsigned long long q9u[9];
#pragma unroll
  for (int k = 0; k < 9; ++k) {
    q9u[k] = (unsigned long long)__double_as_longlong(q9d[k]);
    wfin[lane * 9 + k] = q9u[k];
  }
  __threadfence_block();
  if (lane < 16) {
    // stage 1: merge the wave's 4 quads -> per-wave list for query col=lane
#pragma unroll
    for (int qd = 1; qd < 4; ++qd) {
      const unsigned long long* ob = wfin + (qd * 16 + lane) * 9;
      for (int k = 0; k < 9; ++k) {
        unsigned long long key = ob[k];
        if (key >= q9u[8]) break;          // sorted ascending
        unsigned long long cu = key;
#pragma unroll
        for (int kk = 0; kk < 9; ++kk) {
          bool lt = cu < q9u[kk];
          unsigned long long mn = lt ? cu : q9u[kk];
          cu      = lt ? q9u[kk] : cu;
          q9u[kk] = mn;
        }
      }
    }
#pragma unroll
    for (int k = 0; k < 9; ++k) wfin[lane * 9 + k] = q9u[k];
  }
  __syncthreads();
  // stage 2: wave 0 merges the 4 per-wave lists (candidate quarters)
  if (wv == 0 && lane < 16) {
#pragma unroll
    for (int ow = 1; ow < 4; ++ow) {
      const unsigned long long* ob = lds + ow * 1024 + lane * 9;
      for (int k = 0; k < 9; ++k) {
        unsigned long long key = ob[k];
        if (key >= q9u[8]) break;          // sorted ascending
        unsigned long long cu = key;
#pragma unroll
        for (int kk = 0; kk < 9; ++kk) {
          bool lt = cu < q9u[kk];
          unsigned long long mn = lt ? cu : q9u[kk];
          cu      = lt ? q9u[kk] : cu;
          q9u[kk] = mn;
        }
      }
    }
    int i = qt * 16 + lane;
#pragma unroll
    for (int k = 0; k < 9; ++k) part[(size_t)(k * SPL + sp) * NN + i] = q9u[k];
  }
}

// ---------- kernel 3: merge SPL sorted partial lists -> nbr, deg ----------
__global__ __launch_bounds__(64) void merge_kernel(const unsigned long long* __restrict__ part,
                                                   int* __restrict__ nbr,
                                                   int* __restrict__ deg) {
  int i = blockIdx.x * 64 + threadIdx.x;
  unsigned long long q9[9];
#pragma unroll
  for (int k = 0; k < 9; ++k) q9[k] = ~0ull;
  for (int s = 0; s < SPL; ++s) {
    for (int k = 0; k < 9; ++k) {
      unsigned long long key = part[(size_t)(k * SPL + s) * NN + i];
      if (key >= q9[8]) break;   // list k-sorted ascending
      unsigned long long cu = key;
#pragma unroll
      for (int m = 0; m < 9; ++m) {
        bool lt = cu < q9[m];
        unsigned long long mn = lt ? cu : q9[m];
        cu    = lt ? q9[m] : cu;
        q9[m] = mn;
      }
    }
  }
  int outi[9];
#pragma unroll
  for (int k = 0; k < 9; ++k) outi[k] = (int)(q9[k] & 0x3FFFull);
  // node 16383 sits alone in "batch 4": top_k over one valid entry + (-inf) ties
  // -> neighbors {16383, 0,1,...,7} (lowest-index tie-break). Matters for deg[0..7].
  if (i == NN - 1) {
    outi[0] = NN - 1;
#pragma unroll
    for (int k = 1; k < 9; ++k) outi[k] = k - 1;
  }
#pragma unroll
  for (int k = 0; k < 9; ++k) {
    nbr[i * 9 + k] = outi[k];
    atomicAdd(&deg[outi[k]], 1);
  }
}

// ---------- kernel 4: tx1 gather + out = relu(xf@W0 + tx1@W1 + b) ----------
__global__ __launch_bounds__(256) void out_kernel(const float* __restrict__ xg,
                                                  const int* __restrict__ nbr,
                                                  const int* __restrict__ deg,
                                                  const float* __restrict__ W0,
                                                  const float* __restrict__ W1,
                                                  const float* __restrict__ bias,
                                                  float* __restrict__ out) {
  __shared__ float w0s[48 * 48], w1s[48 * 48], bsh[48];
  __shared__ __align__(16) float xr[64 * 48];
  __shared__ float tx[64 * 48];
  __shared__ float wd[64][9];
  __shared__ int   jn[64][9];
  __shared__ float din[64];
  int tid = threadIdx.x;
  int r0  = blockIdx.x * 64;

  for (int p = tid; p < 2304; p += 256) { w0s[p] = W0[p]; w1s[p] = W1[p]; }
  if (tid < 48) bsh[tid] = bias[tid];
  if (tid < 64) {
    int d = deg[r0 + tid];
    din[tid] = d > 0 ? rsqrtf((float)d) : 0.0f;
  }
  const float4* xg4 = (const float4*)xg;
  float4* xr4 = (float4*)xr;
  for (int p = tid; p < 768; p += 256) {
    int r = p / 12, q = p - r * 12;
    xr4[r * 12 + q] = xg4[(r0 + r) * 13 + q];
  }
  for (int p = tid; p < 576; p += 256) {
    int r = p / 9, k = p - r * 9;
    int j = nbr[(r0 + r) * 9 + k];
    jn[r][k] = j;
    int d = deg[j];
    wd[r][k] = d > 0 ? rsqrtf((float)d) : 0.0f;
  }
  __syncthreads();

  for (int p = tid; p < 3072; p += 256) {
    int r = p / 48, ch = p - r * 48;
    float s = 0.f;
#pragma unroll
    for (int k = 0; k < 9; ++k) s += wd[r][k] * xg[jn[r][k] * 52 + ch];
    tx[r * 48 + ch] = -din[r] * s;
  }
  __syncthreads();

  for (int p = tid; p < 3072; p += 256) {
    int r = p / 48, o = p - r * 48;
    float acc = bsh[o];
#pragma unroll
    for (int cc = 0; cc < 48; ++cc)
      acc += xr[r * 48 + cc] * w0s[cc * 48 + o] + tx[r * 48 + cc] * w1s[cc * 48 + o];
    out[(r0 + r) * 48 + o] = fmaxf(acc, 0.f);
  }
}

extern "C" void kernel_launch(void* const* d_in, const int* in_sizes, int n_in,
                              void* d_out, int out_size, void* d_ws, size_t ws_size,
                              hipStream_t stream) {
  const float* x  = (const float*)d_in[0];
  const float* W0 = (const float*)d_in[1];
  const float* W1 = (const float*)d_in[2];
  const float* b  = (const float*)d_in[3];
  float* out = (float*)d_out;
  char* ws = (char*)d_ws;
  float*          xg   = (float*)(ws);                       // 3,407,872 B
  unsigned short* xh   = (unsigned short*)(ws + 3407872);    // 2,097,152 B
  unsigned short* xl   = (unsigned short*)(ws + 5505024);    // 2,097,152 B
  float*          sqv  = (float*)(ws + 7602176);             //    65,536 B
  int*            nbr  = (int*)(ws + 7667712);               //   589,824 B
  int*            deg  = (int*)(ws + 8257536);               //    65,536 B
  unsigned long long* part = (unsigned long long*)(ws + 8323072);  // 4,718,592 B

  prep_kernel<<<256, 256, 0, stream>>>(x, xg, xh, xl, sqv, deg);
  knn_kernel<<<4096, 256, 0, stream>>>(xh, xl, sqv, part);
  merge_kernel<<<256, 64, 0, stream>>>(part, nbr, deg);
  out_kernel<<<256, 256, 0, stream>>>(xg, nbr, deg, W0, W1, b, out);
}

// Round 4
// 357.501 us; speedup vs baseline: 1.0676x; 1.0676x over previous
//
#include <hip/hip_runtime.h>

#define NN 16384   // total nodes (4*64*64)
#define CC 48      // channels
#define SPL 4      // j-stream splits (part layout unchanged)

typedef __attribute__((ext_vector_type(8))) short bf16x8;
typedef __attribute__((ext_vector_type(4))) float f32x4;

__device__ __forceinline__ unsigned short f2bf(float f) {
  unsigned u = __float_as_uint(f);
  unsigned r = ((u >> 16) & 1u) + 0x7fffu;   // RNE
  return (unsigned short)((u + r) >> 16);
}
__device__ __forceinline__ float bf2f(unsigned short h) {
  return __uint_as_float(((unsigned)h) << 16);
}

// Parallel sorted-insert (ascending 9-queue), med3-identity form: 17 ops, dep depth 2.
// f64 version: used ONLY in the final phase (~12 inserts) on packed
// positive-denormal keys (f64 bit order == u64 order for positive values;
// f64 denormals are always IEEE on CDNA — never flushed).
__device__ __forceinline__ void ins9(double c, double q[9]) {
  double m1 = fmin(q[1], c), m2 = fmin(q[2], c), m3 = fmin(q[3], c),
         m4 = fmin(q[4], c), m5 = fmin(q[5], c), m6 = fmin(q[6], c),
         m7 = fmin(q[7], c), m8 = fmin(q[8], c);
  double n0 = fmin(q[0], c);
  double n1 = fmax(q[0], m1), n2 = fmax(q[1], m2), n3 = fmax(q[2], m3),
         n4 = fmax(q[3], m4), n5 = fmax(q[4], m5), n6 = fmax(q[5], m6),
         n7 = fmax(q[6], m7), n8 = fmax(q[7], m8);
  q[0] = n0; q[1] = n1; q[2] = n2; q[3] = n3; q[4] = n4;
  q[5] = n5; q[6] = n6; q[7] = n7; q[8] = n8;
}

// u32 version for the hot loop: v_min_u32/v_max_u32 full-rate (2 cyc) vs the
// half/quarter-rate DP pipe (R2 busy-cycle math: ~94us VALU issue, ~75% f64).
__device__ __forceinline__ void ins9u(unsigned c, unsigned q[9]) {
  unsigned m1 = min(q[1], c), m2 = min(q[2], c), m3 = min(q[3], c),
           m4 = min(q[4], c), m5 = min(q[5], c), m6 = min(q[6], c),
           m7 = min(q[7], c), m8 = min(q[8], c);
  unsigned n0 = min(q[0], c);
  unsigned n1 = max(q[0], m1), n2 = max(q[1], m2), n3 = max(q[2], m3),
           n4 = max(q[3], m4), n5 = max(q[4], m5), n6 = max(q[5], m6),
           n7 = max(q[6], m7), n8 = max(q[7], m8);
  q[0] = n0; q[1] = n1; q[2] = n2; q[3] = n3; q[4] = n4;
  q[5] = n5; q[6] = n6; q[7] = n7; q[8] = n8;
}

// ---------- kernel 1: [B,C,H,W] -> xg[N][52] fp32, xh/xl[N][64] bf16 split, sqv[N] ----------
__global__ __launch_bounds__(256) void prep_kernel(const float* __restrict__ x,
                                                   float* __restrict__ xg,
                                                   unsigned short* __restrict__ xh,
                                                   unsigned short* __restrict__ xl,
                                                   float* __restrict__ sqv,
                                                   int* __restrict__ deg) {
  __shared__ float tile[48][65];   // +1 pad
  __shared__ float sqcol[64];
  int tid = threadIdx.x;
  int b   = blockIdx.x >> 6;          // batch image 0..3
  int hw0 = (blockIdx.x & 63) << 6;   // 64-wide hw tile
  if (tid < 64) deg[blockIdx.x * 64 + tid] = 0;
#pragma unroll
  for (int p = 0; p < 12; ++p) {
    int it = tid + p * 256;
    int r = it >> 6, col = it & 63;
    tile[r][col] = x[(b * 48 + r) * 4096 + hw0 + col];
  }
  __syncthreads();
  if (tid < 64) {
    float s = 0.f;
#pragma unroll
    for (int r = 0; r < 48; ++r) { float v = tile[r][tid]; s += v * v; }
    sqcol[tid] = s;
    int node = b * 4096 + hw0 + tid;
    sqv[node] = (node == NN - 1) ? __builtin_inff() : s;
  }
  __syncthreads();
  float4* xg4 = (float4*)xg;
#pragma unroll
  for (int p = 0; p < 4; ++p) {
    int it = tid + p * 256;
    if (it < 832) {
      int col = it / 13;
      int q   = it - col * 13;
      float4 v;
      if (q < 12) {
        v.x = tile[q * 4 + 0][col]; v.y = tile[q * 4 + 1][col];
        v.z = tile[q * 4 + 2][col]; v.w = tile[q * 4 + 3][col];
      } else {
        v.x = sqcol[col]; v.y = 0.f; v.z = 0.f; v.w = 0.f;
      }
      xg4[(b * 4096 + hw0 + col) * 13 + q] = v;
    }
  }
  // bf16 hi/lo split, channels padded 48..63 with zeros
#pragma unroll
  for (int p = 0; p < 16; ++p) {
    int it = tid + p * 256;          // 4096 = 64 nodes x 64 ch
    int col = it >> 6, ch = it & 63;
    float v = (ch < 48) ? tile[ch][col] : 0.f;
    unsigned short h = f2bf(v);
    unsigned short l = f2bf(v - bf2f(h));
    size_t o = (size_t)(b * 4096 + hw0 + col) * 64 + ch;
    xh[o] = h;
    xl[o] = l;
  }
}

// ---------- kernel 2: MFMA distance + two-pass exact top-9 ----------
// R3 post-mortem: logic verified but 3 stall sources (pass-2 unprefetched,
// 32KB LDS -> 5 blocks/CU, serial break-loop final phase). R4 fixes:
//   - pass 2 uses the SAME double-buffer prefetch as pass 1
//   - stack depth 16 -> 12 (pushes/lane = exactly 9 + exact-k32-tie surplus;
//     the threshold is the FINAL 9th-best) => LDS 24KB, 6 blocks/CU
//   - final phase: fixed 12 trips, reads batched 4-wide into regs (grouped
//     ds_read_b64 + single wait instead of read->insert->read serialization)
// Selection semantics identical to R3 (passed): pass-1 u32 value-only queue,
// pass-2 recompute (bit-exact) pushes (k32<<14)|j for k32 <= thresh, final
// f64-viewed u64 ins9 gives exact (dist, j)-ordered top-9 incl. tie-break.
__global__ __launch_bounds__(256, 4) void knn_kernel(const unsigned short* __restrict__ xh,
                                                     const unsigned short* __restrict__ xl,
                                                     const float* __restrict__ sqv,
                                                     unsigned long long* __restrict__ part) {
  // per-wave 6KB region: stack [12 slots][64 lanes] u64, overlaid after stack
  // death by fin [64 lanes][9] u64 (within-wave DS ops are in-order; cross-wave
  // reads happen only after __syncthreads).
  __shared__ unsigned long long lds[4 * 12 * 64];   // 24 KB
  int tid = threadIdx.x, wv = tid >> 6, lane = tid & 63;
  int qt = blockIdx.x & 1023, sp = blockIdx.x >> 10;
  int col = lane & 15, quad = lane >> 4;
  int batch = qt >> 8;
  int js = batch * 4096 + sp * 1024;
  int cbase = js + wv * 256;          // this wave's candidate quarter
  unsigned long long* wstk = lds + wv * 768;   // [s*64 + lane]
  unsigned long long* wfin = lds + wv * 768;   // [l*9 + k] overlay

  // resident B-frags (queries)
  int qnode = qt * 16 + col;
  bf16x8 bh0 = *(const bf16x8*)(xh + (size_t)qnode * 64 + quad * 8);
  bf16x8 bh1 = *(const bf16x8*)(xh + (size_t)qnode * 64 + 32 + quad * 8);
  bf16x8 bl0 = *(const bf16x8*)(xl + (size_t)qnode * 64 + quad * 8);
  bf16x8 bl1 = *(const bf16x8*)(xl + (size_t)qnode * 64 + 32 + quad * 8);

  unsigned qv[9];
#pragma unroll
  for (int k = 0; k < 9; ++k) qv[k] = 0xFFFFFFFFu;

  // ---- pass 1: u32 value-only queue (prefetched, same as verified R3) ----
  {
    const unsigned short* pah = xh + ((size_t)(cbase + col) * 64 + quad * 8);
    const unsigned short* pal = xl + ((size_t)(cbase + col) * 64 + quad * 8);
    const float*          psq = sqv + (cbase + quad * 4);
    bf16x8 nh0 = *(const bf16x8*)(pah);
    bf16x8 nh1 = *(const bf16x8*)(pah + 32);
    bf16x8 nl0 = *(const bf16x8*)(pal);
    bf16x8 nl1 = *(const bf16x8*)(pal + 32);
    float4 nsq = *(const float4*)(psq);

    for (int t = 0; t < 16; ++t) {
      bf16x8 ch0 = nh0, ch1 = nh1, cl0 = nl0, cl1 = nl1;
      float4 csq = nsq;
      int adv = (t < 15) ? 1024 : 0;       // 16 nodes * 64 ch
      pah += adv; pal += adv;
      nh0 = *(const bf16x8*)(pah);
      nh1 = *(const bf16x8*)(pah + 32);
      nl0 = *(const bf16x8*)(pal);
      nl1 = *(const bf16x8*)(pal + 32);
      psq += (t < 15) ? 16 : 0;
      nsq = *(const float4*)(psq);

      f32x4 acc = {0.f, 0.f, 0.f, 0.f};
      acc = __builtin_amdgcn_mfma_f32_16x16x32_bf16(ch0, bh0, acc, 0, 0, 0);
      acc = __builtin_amdgcn_mfma_f32_16x16x32_bf16(ch1, bh1, acc, 0, 0, 0);
      acc = __builtin_amdgcn_mfma_f32_16x16x32_bf16(ch0, bl0, acc, 0, 0, 0);
      acc = __builtin_amdgcn_mfma_f32_16x16x32_bf16(ch1, bl1, acc, 0, 0, 0);
      acc = __builtin_amdgcn_mfma_f32_16x16x32_bf16(cl0, bh0, acc, 0, 0, 0);
      acc = __builtin_amdgcn_mfma_f32_16x16x32_bf16(cl1, bh1, acc, 0, 0, 0);

      float sq4[4] = {csq.x, csq.y, csq.z, csq.w};
#pragma unroll
      for (int reg = 0; reg < 4; ++reg) {
        float d = fmaf(-2.f, acc[reg], sq4[reg]);
        unsigned k32 = __float_as_uint(d);
        k32 = ((int)k32 >= 0) ? (k32 | 0x80000000u) : ~k32;   // sortable map
        ins9u(k32, qv);
      }
    }
  }
  unsigned thresh = qv[8];   // exact 9th-smallest k32 value for this lane

  // ---- pass 2: prefetched recompute (bit-exact) + push matches to LDS stack ----
  int cnt = 0;
  int jb = cbase + quad * 4;          // j = jb + t*16 + reg
  {
    const unsigned short* pah = xh + ((size_t)(cbase + col) * 64 + quad * 8);
    const unsigned short* pal = xl + ((size_t)(cbase + col) * 64 + quad * 8);
    const float*          psq = sqv + (cbase + quad * 4);
    bf16x8 nh0 = *(const bf16x8*)(pah);
    bf16x8 nh1 = *(const bf16x8*)(pah + 32);
    bf16x8 nl0 = *(const bf16x8*)(pal);
    bf16x8 nl1 = *(const bf16x8*)(pal + 32);
    float4 nsq = *(const float4*)(psq);

    for (int t = 0; t < 16; ++t) {
      bf16x8 ch0 = nh0, ch1 = nh1, cl0 = nl0, cl1 = nl1;
      float4 csq = nsq;
      int adv = (t < 15) ? 1024 : 0;
      pah += adv; pal += adv;
      nh0 = *(const bf16x8*)(pah);
      nh1 = *(const bf16x8*)(pah + 32);
      nl0 = *(const bf16x8*)(pal);
      nl1 = *(const bf16x8*)(pal + 32);
      psq += (t < 15) ? 16 : 0;
      nsq = *(const float4*)(psq);

      f32x4 acc = {0.f, 0.f, 0.f, 0.f};
      acc = __builtin_amdgcn_mfma_f32_16x16x32_bf16(ch0, bh0, acc, 0, 0, 0);
      acc = __builtin_amdgcn_mfma_f32_16x16x32_bf16(ch1, bh1, acc, 0, 0, 0);
      acc = __builtin_amdgcn_mfma_f32_16x16x32_bf16(ch0, bl0, acc, 0, 0, 0);
      acc = __builtin_amdgcn_mfma_f32_16x16x32_bf16(ch1, bl1, acc, 0, 0, 0);
      acc = __builtin_amdgcn_mfma_f32_16x16x32_bf16(cl0, bh0, acc, 0, 0, 0);
      acc = __builtin_amdgcn_mfma_f32_16x16x32_bf16(cl1, bh1, acc, 0, 0, 0);

      float sq4[4] = {csq.x, csq.y, csq.z, csq.w};
#pragma unroll
      for (int reg = 0; reg < 4; ++reg) {
        float d = fmaf(-2.f, acc[reg], sq4[reg]);
        unsigned k32 = __float_as_uint(d);
        k32 = ((int)k32 >= 0) ? (k32 | 0x80000000u) : ~k32;
        if (k32 <= thresh) {
          int slot = min(cnt, 11);           // clamp: no cross-lane corruption
          wstk[slot * 64 + lane] =
              ((unsigned long long)k32 << 14) | (unsigned)(jb + t * 16 + reg);
          cnt++;
        }
      }
    }
  }

  // ---- final: exact (k32,j)-ordered top-9 from <=12 stack entries ----
  // Fixed trip count, reads batched 4-wide (grouped ds_read_b64, one wait).
  double q9d[9];
#pragma unroll
  for (int k = 0; k < 9; ++k) q9d[k] = __builtin_inf();
#pragma unroll
  for (int sb = 0; sb < 3; ++sb) {
    unsigned long long sv0 = wstk[(sb * 4 + 0) * 64 + lane];
    unsigned long long sv1 = wstk[(sb * 4 + 1) * 64 + lane];
    unsigned long long sv2 = wstk[(sb * 4 + 2) * 64 + lane];
    unsigned long long sv3 = wstk[(sb * 4 + 3) * 64 + lane];
    double k0 = (sb * 4 + 0 < cnt) ? __longlong_as_double((long long)sv0) : __builtin_inf();
    double k1 = (sb * 4 + 1 < cnt) ? __longlong_as_double((long long)sv1) : __builtin_inf();
    double k2 = (sb * 4 + 2 < cnt) ? __longlong_as_double((long long)sv2) : __builtin_inf();
    double k3 = (sb * 4 + 3 < cnt) ? __longlong_as_double((long long)sv3) : __builtin_inf();
    ins9(k0, q9d);
    ins9(k1, q9d);
    ins9(k2, q9d);
    ins9(k3, q9d);
  }
  // bit pattern IS the packed (k32<<14)|j key (positive denormal)
  unsigned long long q9u[9];
#pragma unroll
  for (int k = 0; k < 9; ++k) {
    q9u[k] = (unsigned long long)__double_as_longlong(q9d[k]);
    wfin[lane * 9 + k] = q9u[k];
  }
  __threadfence_block();
  if (lane < 16) {
    // stage 1: merge the wave's 4 quads -> per-wave list for query col=lane
#pragma unroll
    for (int qd = 1; qd < 4; ++qd) {
      const unsigned long long* ob = wfin + (qd * 16 + lane) * 9;
      for (int k = 0; k < 9; ++k) {
        unsigned long long key = ob[k];
        if (key >= q9u[8]) break;          // sorted ascending
        unsigned long long cu = key;
#pragma unroll
        for (int kk = 0; kk < 9; ++kk) {
          bool lt = cu < q9u[kk];
          unsigned long long mn = lt ? cu : q9u[kk];
          cu      = lt ? q9u[kk] : cu;
          q9u[kk] = mn;
        }
      }
    }
#pragma unroll
    for (int k = 0; k < 9; ++k) wfin[lane * 9 + k] = q9u[k];
  }
  __syncthreads();
  // stage 2: wave 0 merges the 4 per-wave lists (candidate quarters)
  if (wv == 0 && lane < 16) {
#pragma unroll
    for (int ow = 1; ow < 4; ++ow) {
      const unsigned long long* ob = lds + ow * 768 + lane * 9;
      for (int k = 0; k < 9; ++k) {
        unsigned long long key = ob[k];
        if (key >= q9u[8]) break;          // sorted ascending
        unsigned long long cu = key;
#pragma unroll
        for (int kk = 0; kk < 9; ++kk) {
          bool lt = cu < q9u[kk];
          unsigned long long mn = lt ? cu : q9u[kk];
          cu      = lt ? q9u[kk] : cu;
          q9u[kk] = mn;
        }
      }
    }
    int i = qt * 16 + lane;
#pragma unroll
    for (int k = 0; k < 9; ++k) part[(size_t)(k * SPL + sp) * NN + i] = q9u[k];
  }
}

// ---------- kernel 3: merge SPL sorted partial lists -> nbr, deg ----------
__global__ __launch_bounds__(64) void merge_kernel(const unsigned long long* __restrict__ part,
                                                   int* __restrict__ nbr,
                                                   int* __restrict__ deg) {
  int i = blockIdx.x * 64 + threadIdx.x;
  unsigned long long q9[9];
#pragma unroll
  for (int k = 0; k < 9; ++k) q9[k] = ~0ull;
  for (int s = 0; s < SPL; ++s) {
    for (int k = 0; k < 9; ++k) {
      unsigned long long key = part[(size_t)(k * SPL + s) * NN + i];
      if (key >= q9[8]) break;   // list k-sorted ascending
      unsigned long long cu = key;
#pragma unroll
      for (int m = 0; m < 9; ++m) {
        bool lt = cu < q9[m];
        unsigned long long mn = lt ? cu : q9[m];
        cu    = lt ? q9[m] : cu;
        q9[m] = mn;
      }
    }
  }
  int outi[9];
#pragma unroll
  for (int k = 0; k < 9; ++k) outi[k] = (int)(q9[k] & 0x3FFFull);
  // node 16383 sits alone in "batch 4": top_k over one valid entry + (-inf) ties
  // -> neighbors {16383, 0,1,...,7} (lowest-index tie-break). Matters for deg[0..7].
  if (i == NN - 1) {
    outi[0] = NN - 1;
#pragma unroll
    for (int k = 1; k < 9; ++k) outi[k] = k - 1;
  }
#pragma unroll
  for (int k = 0; k < 9; ++k) {
    nbr[i * 9 + k] = outi[k];
    atomicAdd(&deg[outi[k]], 1);
  }
}

// ---------- kernel 4: tx1 gather + out = relu(xf@W0 + tx1@W1 + b) ----------
__global__ __launch_bounds__(256) void out_kernel(const float* __restrict__ xg,
                                                  const int* __restrict__ nbr,
                                                  const int* __restrict__ deg,
                                                  const float* __restrict__ W0,
                                                  const float* __restrict__ W1,
                                                  const float* __restrict__ bias,
                                                  float* __restrict__ out) {
  __shared__ float w0s[48 * 48], w1s[48 * 48], bsh[48];
  __shared__ __align__(16) float xr[64 * 48];
  __shared__ float tx[64 * 48];
  __shared__ float wd[64][9];
  __shared__ int   jn[64][9];
  __shared__ float din[64];
  int tid = threadIdx.x;
  int r0  = blockIdx.x * 64;

  for (int p = tid; p < 2304; p += 256) { w0s[p] = W0[p]; w1s[p] = W1[p]; }
  if (tid < 48) bsh[tid] = bias[tid];
  if (tid < 64) {
    int d = deg[r0 + tid];
    din[tid] = d > 0 ? rsqrtf((float)d) : 0.0f;
  }
  const float4* xg4 = (const float4*)xg;
  float4* xr4 = (float4*)xr;
  for (int p = tid; p < 768; p += 256) {
    int r = p / 12, q = p - r * 12;
    xr4[r * 12 + q] = xg4[(r0 + r) * 13 + q];
  }
  for (int p = tid; p < 576; p += 256) {
    int r = p / 9, k = p - r * 9;
    int j = nbr[(r0 + r) * 9 + k];
    jn[r][k] = j;
    int d = deg[j];
    wd[r][k] = d > 0 ? rsqrtf((float)d) : 0.0f;
  }
  __syncthreads();

  for (int p = tid; p < 3072; p += 256) {
    int r = p / 48, ch = p - r * 48;
    float s = 0.f;
#pragma unroll
    for (int k = 0; k < 9; ++k) s += wd[r][k] * xg[jn[r][k] * 52 + ch];
    tx[r * 48 + ch] = -din[r] * s;
  }
  __syncthreads();

  for (int p = tid; p < 3072; p += 256) {
    int r = p / 48, o = p - r * 48;
    float acc = bsh[o];
#pragma unroll
    for (int cc = 0; cc < 48; ++cc)
      acc += xr[r * 48 + cc] * w0s[cc * 48 + o] + tx[r * 48 + cc] * w1s[cc * 48 + o];
    out[(r0 + r) * 48 + o] = fmaxf(acc, 0.f);
  }
}

extern "C" void kernel_launch(void* const* d_in, const int* in_sizes, int n_in,
                              void* d_out, int out_size, void* d_ws, size_t ws_size,
                              hipStream_t stream) {
  const float* x  = (const float*)d_in[0];
  const float* W0 = (const float*)d_in[1];
  const float* W1 = (const float*)d_in[2];
  const float* b  = (const float*)d_in[3];
  float* out = (float*)d_out;
  char* ws = (char*)d_ws;
  float*          xg   = (float*)(ws);                       // 3,407,872 B
  unsigned short* xh   = (unsigned short*)(ws + 3407872);    // 2,097,152 B
  unsigned short* xl   = (unsigned short*)(ws + 5505024);    // 2,097,152 B
  float*          sqv  = (float*)(ws + 7602176);             //    65,536 B
  int*            nbr  = (int*)(ws + 7667712);               //   589,824 B
  int*            deg  = (int*)(ws + 8257536);               //    65,536 B
  unsigned long long* part = (unsigned long long*)(ws + 8323072);  // 4,718,592 B

  prep_kernel<<<256, 256, 0, stream>>>(x, xg, xh, xl, sqv, deg);
  knn_kernel<<<4096, 256, 0, stream>>>(xh, xl, sqv, part);
  merge_kernel<<<256, 64, 0, stream>>>(part, nbr, deg);
  out_kernel<<<256, 256, 0, stream>>>(xg, nbr, deg, W0, W1, b, out);
}

// Round 5
// 268.989 us; speedup vs baseline: 1.4190x; 1.3291x over previous
//
#include <hip/hip_runtime.h>

#define NN 16384   // total nodes (4*64*64)
#define CC 48      // channels
#define SPL 4      // j-stream splits (part layout unchanged)

typedef __attribute__((ext_vector_type(8))) short bf16x8;
typedef __attribute__((ext_vector_type(4))) float f32x4;

__device__ __forceinline__ unsigned short f2bf(float f) {
  unsigned u = __float_as_uint(f);
  unsigned r = ((u >> 16) & 1u) + 0x7fffu;   // RNE
  return (unsigned short)((u + r) >> 16);
}
__device__ __forceinline__ float bf2f(unsigned short h) {
  return __uint_as_float(((unsigned)h) << 16);
}

// Payload-carrying parallel sorted-insert into ascending (qv, pj)[0..8].
// R4 post-mortem: f64 fmin/fmax measured ~6.7 cyc/op (R0 busy-cycle fit) and
// both two-pass recovery attempts (R3/R4) were issue-inflated. This carries
// the neighbor index j as an explicit u32 payload updated by the SAME cmp
// masks as the value: 9 v_cmp_lt_u32 + 34 v_cndmask = 43 full-rate ops/insert
// (~86 cyc) vs f64 ins9's ~114, zero DP-pipe pressure, no decode epilogue.
// Strict < keeps exact (k32, j) order: an equal-k32 later candidate (higher j,
// since j ascends within a lane's stream) ranks after the incumbent —
// identical to the verified k32*256+ordinal fmin semantics.
// In-place descending update is safe: slot k reads old q[k-1] before slot k-1
// is overwritten.
__device__ __forceinline__ void ins9p(unsigned c, unsigned pc,
                                      unsigned qv[9], unsigned pj[9]) {
  bool l0 = c < qv[0], l1 = c < qv[1], l2 = c < qv[2], l3 = c < qv[3],
       l4 = c < qv[4], l5 = c < qv[5], l6 = c < qv[6], l7 = c < qv[7],
       l8 = c < qv[8];
  qv[8] = l7 ? qv[7] : (l8 ? c : qv[8]);  pj[8] = l7 ? pj[7] : (l8 ? pc : pj[8]);
  qv[7] = l6 ? qv[6] : (l7 ? c : qv[7]);  pj[7] = l6 ? pj[6] : (l7 ? pc : pj[7]);
  qv[6] = l5 ? qv[5] : (l6 ? c : qv[6]);  pj[6] = l5 ? pj[5] : (l6 ? pc : pj[6]);
  qv[5] = l4 ? qv[4] : (l5 ? c : qv[5]);  pj[5] = l4 ? pj[4] : (l5 ? pc : pj[5]);
  qv[4] = l3 ? qv[3] : (l4 ? c : qv[4]);  pj[4] = l3 ? pj[3] : (l4 ? pc : pj[4]);
  qv[3] = l2 ? qv[2] : (l3 ? c : qv[3]);  pj[3] = l2 ? pj[2] : (l3 ? pc : pj[3]);
  qv[2] = l1 ? qv[1] : (l2 ? c : qv[2]);  pj[2] = l1 ? pj[1] : (l2 ? pc : pj[2]);
  qv[1] = l0 ? qv[0] : (l1 ? c : qv[1]);  pj[1] = l0 ? pj[0] : (l1 ? pc : pj[1]);
  qv[0] = l0 ? c : qv[0];                 pj[0] = l0 ? pc : pj[0];
}

// ---------- kernel 1: [B,C,H,W] -> xg[N][52] fp32, xh/xl[N][64] bf16 split, sqv[N] ----------
// Also zeroes deg[]; sqv[16383] = +inf (excludes the lone "batch 4" node as a
// candidate for batch-3 queries at zero hot-loop cost: dist = inf, never ranked).
__global__ __launch_bounds__(256) void prep_kernel(const float* __restrict__ x,
                                                   float* __restrict__ xg,
                                                   unsigned short* __restrict__ xh,
                                                   unsigned short* __restrict__ xl,
                                                   float* __restrict__ sqv,
                                                   int* __restrict__ deg) {
  __shared__ float tile[48][65];   // +1 pad
  __shared__ float sqcol[64];
  int tid = threadIdx.x;
  int b   = blockIdx.x >> 6;          // batch image 0..3
  int hw0 = (blockIdx.x & 63) << 6;   // 64-wide hw tile
  if (tid < 64) deg[blockIdx.x * 64 + tid] = 0;
#pragma unroll
  for (int p = 0; p < 12; ++p) {
    int it = tid + p * 256;
    int r = it >> 6, col = it & 63;
    tile[r][col] = x[(b * 48 + r) * 4096 + hw0 + col];
  }
  __syncthreads();
  if (tid < 64) {
    float s = 0.f;
#pragma unroll
    for (int r = 0; r < 48; ++r) { float v = tile[r][tid]; s += v * v; }
    sqcol[tid] = s;
    int node = b * 4096 + hw0 + tid;
    sqv[node] = (node == NN - 1) ? __builtin_inff() : s;
  }
  __syncthreads();
  float4* xg4 = (float4*)xg;
#pragma unroll
  for (int p = 0; p < 4; ++p) {
    int it = tid + p * 256;
    if (it < 832) {
      int col = it / 13;
      int q   = it - col * 13;
      float4 v;
      if (q < 12) {
        v.x = tile[q * 4 + 0][col]; v.y = tile[q * 4 + 1][col];
        v.z = tile[q * 4 + 2][col]; v.w = tile[q * 4 + 3][col];
      } else {
        v.x = sqcol[col]; v.y = 0.f; v.z = 0.f; v.w = 0.f;
      }
      xg4[(b * 4096 + hw0 + col) * 13 + q] = v;
    }
  }
  // bf16 hi/lo split, channels padded 48..63 with zeros
#pragma unroll
  for (int p = 0; p < 16; ++p) {
    int it = tid + p * 256;          // 4096 = 64 nodes x 64 ch
    int col = it >> 6, ch = it & 63;
    float v = (ch < 48) ? tile[ch][col] : 0.f;
    unsigned short h = f2bf(v);
    unsigned short l = f2bf(v - bf2f(h));
    size_t o = (size_t)(b * 4096 + hw0 + col) * 64 + ch;
    xh[o] = h;
    xl[o] = l;
  }
}

// ---------- kernel 2: MFMA distance + single-pass u32+payload exact top-9 ----------
// Structure = verified R2 skeleton (4096 blocks, one (qt,sp) per block, 4 waves
// x 16 tiles, fin staging + 2-stage merge + part layout all byte-identical).
// ONLY change: the queue. Value = sortable u32 k32, payload = j (carried
// through the same cndmask network). No f64 anywhere; no decode epilogue
// (q9u = (value<<14)|j, 2 ops). Sortedness of q9u preserved: within equal
// values, payloads ascend (strict-< insert + j ascending in-stream).
__global__ __launch_bounds__(256, 4) void knn_kernel(const unsigned short* __restrict__ xh,
                                                     const unsigned short* __restrict__ xl,
                                                     const float* __restrict__ sqv,
                                                     unsigned long long* __restrict__ part) {
  __shared__ unsigned long long fin[4][64][9];   // 18.4 KB, merge staging only
  int tid = threadIdx.x, wv = tid >> 6, lane = tid & 63;
  int qt = blockIdx.x & 1023, sp = blockIdx.x >> 10;
  int col = lane & 15, quad = lane >> 4;
  int batch = qt >> 8;
  int js = batch * 4096 + sp * 1024;
  int cbase = js + wv * 256;          // this wave's candidate quarter

  // resident B-frags (queries)
  int qnode = qt * 16 + col;
  bf16x8 bh0 = *(const bf16x8*)(xh + (size_t)qnode * 64 + quad * 8);
  bf16x8 bh1 = *(const bf16x8*)(xh + (size_t)qnode * 64 + 32 + quad * 8);
  bf16x8 bl0 = *(const bf16x8*)(xl + (size_t)qnode * 64 + quad * 8);
  bf16x8 bl1 = *(const bf16x8*)(xl + (size_t)qnode * 64 + 32 + quad * 8);

  unsigned qv[9], pj[9];
#pragma unroll
  for (int k = 0; k < 9; ++k) { qv[k] = 0xFFFFFFFFu; pj[k] = 0x3FFFu; }

  // prefetch tile 0: A-frags (candidate node cbase + col) + sq float4
  const unsigned short* pah = xh + ((size_t)(cbase + col) * 64 + quad * 8);
  const unsigned short* pal = xl + ((size_t)(cbase + col) * 64 + quad * 8);
  const float*          psq = sqv + (cbase + quad * 4);
  bf16x8 nh0 = *(const bf16x8*)(pah);
  bf16x8 nh1 = *(const bf16x8*)(pah + 32);
  bf16x8 nl0 = *(const bf16x8*)(pal);
  bf16x8 nl1 = *(const bf16x8*)(pal + 32);
  float4 nsq = *(const float4*)(psq);

  int jt = cbase + quad * 4;          // payload base: j = jt + reg, jt += 16/tile
  for (int t = 0; t < 16; ++t) {
    bf16x8 ch0 = nh0, ch1 = nh1, cl0 = nl0, cl1 = nl1;
    float4 csq = nsq;
    int adv = (t < 15) ? 1024 : 0;       // 16 nodes * 64 ch
    pah += adv; pal += adv;
    nh0 = *(const bf16x8*)(pah);
    nh1 = *(const bf16x8*)(pah + 32);
    nl0 = *(const bf16x8*)(pal);
    nl1 = *(const bf16x8*)(pal + 32);
    psq += (t < 15) ? 16 : 0;
    nsq = *(const float4*)(psq);

    f32x4 acc = {0.f, 0.f, 0.f, 0.f};
    acc = __builtin_amdgcn_mfma_f32_16x16x32_bf16(ch0, bh0, acc, 0, 0, 0);  // hi.hi k0-31
    acc = __builtin_amdgcn_mfma_f32_16x16x32_bf16(ch1, bh1, acc, 0, 0, 0);  // hi.hi k32-63
    acc = __builtin_amdgcn_mfma_f32_16x16x32_bf16(ch0, bl0, acc, 0, 0, 0);  // hi.lo
    acc = __builtin_amdgcn_mfma_f32_16x16x32_bf16(ch1, bl1, acc, 0, 0, 0);
    acc = __builtin_amdgcn_mfma_f32_16x16x32_bf16(cl0, bh0, acc, 0, 0, 0);  // lo.hi
    acc = __builtin_amdgcn_mfma_f32_16x16x32_bf16(cl1, bh1, acc, 0, 0, 0);

    float sq4[4] = {csq.x, csq.y, csq.z, csq.w};
#pragma unroll
    for (int reg = 0; reg < 4; ++reg) {
      float d = fmaf(-2.f, acc[reg], sq4[reg]);   // key: sq_j - 2 dot (sq_i dropped)
      unsigned k32 = __float_as_uint(d);
      k32 = ((int)k32 >= 0) ? (k32 | 0x80000000u) : ~k32;   // sortable map
      ins9p(k32, (unsigned)(jt + reg), qv, pj);
    }
    jt += 16;
  }

  // pack (k32, j) -> u64; stage for in-wave quad merge (ascending, exact)
  unsigned long long q9u[9];
#pragma unroll
  for (int k = 0; k < 9; ++k) {
    q9u[k] = ((unsigned long long)qv[k] << 14) | pj[k];
    fin[wv][lane][k] = q9u[k];
  }
  __threadfence_block();
  if (lane < 16) {
    // stage 1: merge the wave's 4 quads -> per-wave list for query col=lane
#pragma unroll
    for (int qd = 1; qd < 4; ++qd) {
      const unsigned long long* ob = fin[wv][qd * 16 + lane];
      for (int k = 0; k < 9; ++k) {
        unsigned long long key = ob[k];
        if (key >= q9u[8]) break;          // sorted ascending
        unsigned long long cu = key;
#pragma unroll
        for (int kk = 0; kk < 9; ++kk) {
          bool lt = cu < q9u[kk];
          unsigned long long mn = lt ? cu : q9u[kk];
          cu      = lt ? q9u[kk] : cu;
          q9u[kk] = mn;
        }
      }
    }
    // restage per-wave merged list (only fin[wv][0..15] touched; own quad
    // reads above covered 16..63, other waves never read fin[wv])
#pragma unroll
    for (int k = 0; k < 9; ++k) fin[wv][lane][k] = q9u[k];
  }
  __syncthreads();
  // stage 2: wave 0 merges the 4 per-wave lists (candidate quarters)
  if (wv == 0 && lane < 16) {
#pragma unroll
    for (int ow = 1; ow < 4; ++ow) {
      const unsigned long long* ob = fin[ow][lane];
      for (int k = 0; k < 9; ++k) {
        unsigned long long key = ob[k];
        if (key >= q9u[8]) break;          // sorted ascending
        unsigned long long cu = key;
#pragma unroll
        for (int kk = 0; kk < 9; ++kk) {
          bool lt = cu < q9u[kk];
          unsigned long long mn = lt ? cu : q9u[kk];
          cu      = lt ? q9u[kk] : cu;
          q9u[kk] = mn;
        }
      }
    }
    int i = qt * 16 + lane;
#pragma unroll
    for (int k = 0; k < 9; ++k) part[(size_t)(k * SPL + sp) * NN + i] = q9u[k];
  }
}

// ---------- kernel 3: merge SPL sorted partial lists -> nbr, deg ----------
__global__ __launch_bounds__(64) void merge_kernel(const unsigned long long* __restrict__ part,
                                                   int* __restrict__ nbr,
                                                   int* __restrict__ deg) {
  int i = blockIdx.x * 64 + threadIdx.x;
  unsigned long long q9[9];
#pragma unroll
  for (int k = 0; k < 9; ++k) q9[k] = ~0ull;
  for (int s = 0; s < SPL; ++s) {
    for (int k = 0; k < 9; ++k) {
      unsigned long long key = part[(size_t)(k * SPL + s) * NN + i];
      if (key >= q9[8]) break;   // list k-sorted ascending
      unsigned long long cu = key;
#pragma unroll
      for (int m = 0; m < 9; ++m) {
        bool lt = cu < q9[m];
        unsigned long long mn = lt ? cu : q9[m];
        cu    = lt ? q9[m] : cu;
        q9[m] = mn;
      }
    }
  }
  int outi[9];
#pragma unroll
  for (int k = 0; k < 9; ++k) outi[k] = (int)(q9[k] & 0x3FFFull);
  // node 16383 sits alone in "batch 4": top_k over one valid entry + (-inf) ties
  // -> neighbors {16383, 0,1,...,7} (lowest-index tie-break). Matters for deg[0..7].
  if (i == NN - 1) {
    outi[0] = NN - 1;
#pragma unroll
    for (int k = 1; k < 9; ++k) outi[k] = k - 1;
  }
#pragma unroll
  for (int k = 0; k < 9; ++k) {
    nbr[i * 9 + k] = outi[k];
    atomicAdd(&deg[outi[k]], 1);
  }
}

// ---------- kernel 4: tx1 gather + out = relu(xf@W0 + tx1@W1 + b) ----------
__global__ __launch_bounds__(256) void out_kernel(const float* __restrict__ xg,
                                                  const int* __restrict__ nbr,
                                                  const int* __restrict__ deg,
                                                  const float* __restrict__ W0,
                                                  const float* __restrict__ W1,
                                                  const float* __restrict__ bias,
                                                  float* __restrict__ out) {
  __shared__ float w0s[48 * 48], w1s[48 * 48], bsh[48];
  __shared__ __align__(16) float xr[64 * 48];
  __shared__ float tx[64 * 48];
  __shared__ float wd[64][9];
  __shared__ int   jn[64][9];
  __shared__ float din[64];
  int tid = threadIdx.x;
  int r0  = blockIdx.x * 64;

  for (int p = tid; p < 2304; p += 256) { w0s[p] = W0[p]; w1s[p] = W1[p]; }
  if (tid < 48) bsh[tid] = bias[tid];
  if (tid < 64) {
    int d = deg[r0 + tid];
    din[tid] = d > 0 ? rsqrtf((float)d) : 0.0f;
  }
  const float4* xg4 = (const float4*)xg;
  float4* xr4 = (float4*)xr;
  for (int p = tid; p < 768; p += 256) {
    int r = p / 12, q = p - r * 12;
    xr4[r * 12 + q] = xg4[(r0 + r) * 13 + q];
  }
  for (int p = tid; p < 576; p += 256) {
    int r = p / 9, k = p - r * 9;
    int j = nbr[(r0 + r) * 9 + k];
    jn[r][k] = j;
    int d = deg[j];
    wd[r][k] = d > 0 ? rsqrtf((float)d) : 0.0f;
  }
  __syncthreads();

  for (int p = tid; p < 3072; p += 256) {
    int r = p / 48, ch = p - r * 48;
    float s = 0.f;
#pragma unroll
    for (int k = 0; k < 9; ++k) s += wd[r][k] * xg[jn[r][k] * 52 + ch];
    tx[r * 48 + ch] = -din[r] * s;
  }
  __syncthreads();

  for (int p = tid; p < 3072; p += 256) {
    int r = p / 48, o = p - r * 48;
    float acc = bsh[o];
#pragma unroll
    for (int cc = 0; cc < 48; ++cc)
      acc += xr[r * 48 + cc] * w0s[cc * 48 + o] + tx[r * 48 + cc] * w1s[cc * 48 + o];
    out[(r0 + r) * 48 + o] = fmaxf(acc, 0.f);
  }
}

extern "C" void kernel_launch(void* const* d_in, const int* in_sizes, int n_in,
                              void* d_out, int out_size, void* d_ws, size_t ws_size,
                              hipStream_t stream) {
  const float* x  = (const float*)d_in[0];
  const float* W0 = (const float*)d_in[1];
  const float* W1 = (const float*)d_in[2];
  const float* b  = (const float*)d_in[3];
  float* out = (float*)d_out;
  char* ws = (char*)d_ws;
  float*          xg   = (float*)(ws);                       // 3,407,872 B
  unsigned short* xh   = (unsigned short*)(ws + 3407872);    // 2,097,152 B
  unsigned short* xl   = (unsigned short*)(ws + 5505024);    // 2,097,152 B
  float*          sqv  = (float*)(ws + 7602176);             //    65,536 B
  int*            nbr  = (int*)(ws + 7667712);               //   589,824 B
  int*            deg  = (int*)(ws + 8257536);               //    65,536 B
  unsigned long long* part = (unsigned long long*)(ws + 8323072);  // 4,718,592 B

  prep_kernel<<<256, 256, 0, stream>>>(x, xg, xh, xl, sqv, deg);
  knn_kernel<<<4096, 256, 0, stream>>>(xh, xl, sqv, part);
  merge_kernel<<<256, 64, 0, stream>>>(part, nbr, deg);
  out_kernel<<<256, 256, 0, stream>>>(xg, nbr, deg, W0, W1, b, out);
}

// Round 6
// 222.970 us; speedup vs baseline: 1.7118x; 1.2064x over previous
//
#include <hip/hip_runtime.h>

#define NN 16384   // total nodes (4*64*64)
#define CC 48      // channels

typedef __attribute__((ext_vector_type(8))) short bf16x8;
typedef __attribute__((ext_vector_type(4))) float f32x4;

__device__ __forceinline__ unsigned short f2bf(float f) {
  unsigned u = __float_as_uint(f);
  unsigned r = ((u >> 16) & 1u) + 0x7fffu;   // RNE
  return (unsigned short)((u + r) >> 16);
}
__device__ __forceinline__ float bf2f(unsigned short h) {
  return __uint_as_float(((unsigned)h) << 16);
}

// Parallel sorted-insert of key c into ascending q[0..8] (verified R0 form).
// Five rounds of measurement: this f64 network (~6 cyc/fmin-fmax issue) beats
// u32 value-only + recompute (R3/R4) and u32+payload cndmask (R5). Keep.
__device__ __forceinline__ void ins9(double c, double q[9]) {
  double m1 = fmin(q[1], c), m2 = fmin(q[2], c), m3 = fmin(q[3], c),
         m4 = fmin(q[4], c), m5 = fmin(q[5], c), m6 = fmin(q[6], c),
         m7 = fmin(q[7], c), m8 = fmin(q[8], c);
  double n0 = fmin(q[0], c);
  double n1 = fmax(q[0], m1), n2 = fmax(q[1], m2), n3 = fmax(q[2], m3),
         n4 = fmax(q[3], m4), n5 = fmax(q[4], m5), n6 = fmax(q[5], m6),
         n7 = fmax(q[6], m7), n8 = fmax(q[7], m8);
  q[0] = n0; q[1] = n1; q[2] = n2; q[3] = n3; q[4] = n4;
  q[5] = n5; q[6] = n6; q[7] = n7; q[8] = n8;
}

// ---------- kernel 1: [B,C,H,W] -> xg[N][52] fp32, xh/xl[N][64] bf16 split, sqv[N] ----------
// Also zeroes deg[]; sqv[16383] = +inf (excludes the lone "batch 4" node as a
// candidate for batch-3 queries at zero hot-loop cost: dist = inf, never ranked).
__global__ __launch_bounds__(256) void prep_kernel(const float* __restrict__ x,
                                                   float* __restrict__ xg,
                                                   unsigned short* __restrict__ xh,
                                                   unsigned short* __restrict__ xl,
                                                   float* __restrict__ sqv,
                                                   int* __restrict__ deg) {
  __shared__ float tile[48][65];   // +1 pad
  __shared__ float sqcol[64];
  int tid = threadIdx.x;
  int b   = blockIdx.x >> 6;          // batch image 0..3
  int hw0 = (blockIdx.x & 63) << 6;   // 64-wide hw tile
  if (tid < 64) deg[blockIdx.x * 64 + tid] = 0;
#pragma unroll
  for (int p = 0; p < 12; ++p) {
    int it = tid + p * 256;
    int r = it >> 6, col = it & 63;
    tile[r][col] = x[(b * 48 + r) * 4096 + hw0 + col];
  }
  __syncthreads();
  if (tid < 64) {
    float s = 0.f;
#pragma unroll
    for (int r = 0; r < 48; ++r) { float v = tile[r][tid]; s += v * v; }
    sqcol[tid] = s;
    int node = b * 4096 + hw0 + tid;
    sqv[node] = (node == NN - 1) ? __builtin_inff() : s;
  }
  __syncthreads();
  float4* xg4 = (float4*)xg;
#pragma unroll
  for (int p = 0; p < 4; ++p) {
    int it = tid + p * 256;
    if (it < 832) {
      int col = it / 13;
      int q   = it - col * 13;
      float4 v;
      if (q < 12) {
        v.x = tile[q * 4 + 0][col]; v.y = tile[q * 4 + 1][col];
        v.z = tile[q * 4 + 2][col]; v.w = tile[q * 4 + 3][col];
      } else {
        v.x = sqcol[col]; v.y = 0.f; v.z = 0.f; v.w = 0.f;
      }
      xg4[(b * 4096 + hw0 + col) * 13 + q] = v;
    }
  }
  // bf16 hi/lo split, channels padded 48..63 with zeros
#pragma unroll
  for (int p = 0; p < 16; ++p) {
    int it = tid + p * 256;          // 4096 = 64 nodes x 64 ch
    int col = it >> 6, ch = it & 63;
    float v = (ch < 48) ? tile[ch][col] : 0.f;
    unsigned short h = f2bf(v);
    unsigned short l = f2bf(v - bf2f(h));
    size_t o = (size_t)(b * 4096 + hw0 + col) * 64 + ch;
    xh[o] = h;
    xl[o] = l;
  }
}

// ---------- kernel 2: MFMA distance + exact f64 top-9, FUSED final merge ----------
// R5 post-mortem: every hot-loop variant lost to R0's (f64 queue, 64-tile
// streams, grid 1024). So the hot loop below is BYTE-IDENTICAL to R0's; the
// structural change is the decomposition: block = one query-tile qt, its 4
// waves = the 4 candidate quarters (cbase = batch*4096 + wv*1024, 64 tiles
// each — same stream length / per-wave overhead as R0). The block's 2-stage
// LDS merge (verified R2-R5) then yields the FINAL top-9, so this kernel
// writes nbr + atomicAdd deg directly — merge_kernel and the 4.6MB part
// buffer are deleted, removing one dispatch + its launch gap + part traffic.
// Key = sortable_u32(dist)*256 + ordinal (od = t*4+reg <= 255, exact 40-bit
// int in f64); decode j = cbase + (o>>2)*16 + quad*4 + (o&3); cross-quad and
// cross-wave merges compare packed (k32<<14)|j u64 — all verified semantics.
__global__ __launch_bounds__(256, 4) void knn_kernel(const unsigned short* __restrict__ xh,
                                                     const unsigned short* __restrict__ xl,
                                                     const float* __restrict__ sqv,
                                                     int* __restrict__ nbr,
                                                     int* __restrict__ deg) {
  __shared__ unsigned long long fin[4][64][9];   // 18.4 KB, merge staging only
  int tid = threadIdx.x, wv = tid >> 6, lane = tid & 63;
  int qt = blockIdx.x;
  int col = lane & 15, quad = lane >> 4;
  int batch = qt >> 8;
  int cbase = batch * 4096 + wv * 1024;   // this wave's candidate quarter

  // resident B-frags (queries)
  int qnode = qt * 16 + col;
  bf16x8 bh0 = *(const bf16x8*)(xh + (size_t)qnode * 64 + quad * 8);
  bf16x8 bh1 = *(const bf16x8*)(xh + (size_t)qnode * 64 + 32 + quad * 8);
  bf16x8 bl0 = *(const bf16x8*)(xl + (size_t)qnode * 64 + quad * 8);
  bf16x8 bl1 = *(const bf16x8*)(xl + (size_t)qnode * 64 + 32 + quad * 8);

  double q9[9];
#pragma unroll
  for (int k = 0; k < 9; ++k) q9[k] = __builtin_inf();

  // prefetch tile 0: A-frags (candidate node cbase + col) + sq float4
  const unsigned short* pah = xh + ((size_t)(cbase + col) * 64 + quad * 8);
  const unsigned short* pal = xl + ((size_t)(cbase + col) * 64 + quad * 8);
  const float*          psq = sqv + (cbase + quad * 4);
  bf16x8 nh0 = *(const bf16x8*)(pah);
  bf16x8 nh1 = *(const bf16x8*)(pah + 32);
  bf16x8 nl0 = *(const bf16x8*)(pal);
  bf16x8 nl1 = *(const bf16x8*)(pal + 32);
  float4 nsq = *(const float4*)(psq);

  double od = 0.0;   // ordinal base = t*4 (exact integer in f64)
  for (int t = 0; t < 64; ++t) {
    bf16x8 ch0 = nh0, ch1 = nh1, cl0 = nl0, cl1 = nl1;
    float4 csq = nsq;
    int adv = (t < 63) ? 1024 : 0;       // 16 nodes * 64 ch
    pah += adv; pal += adv;
    nh0 = *(const bf16x8*)(pah);
    nh1 = *(const bf16x8*)(pah + 32);
    nl0 = *(const bf16x8*)(pal);
    nl1 = *(const bf16x8*)(pal + 32);
    psq += (t < 63) ? 16 : 0;
    nsq = *(const float4*)(psq);

    f32x4 acc = {0.f, 0.f, 0.f, 0.f};
    acc = __builtin_amdgcn_mfma_f32_16x16x32_bf16(ch0, bh0, acc, 0, 0, 0);  // hi.hi k0-31
    acc = __builtin_amdgcn_mfma_f32_16x16x32_bf16(ch1, bh1, acc, 0, 0, 0);  // hi.hi k32-63
    acc = __builtin_amdgcn_mfma_f32_16x16x32_bf16(ch0, bl0, acc, 0, 0, 0);  // hi.lo
    acc = __builtin_amdgcn_mfma_f32_16x16x32_bf16(ch1, bl1, acc, 0, 0, 0);
    acc = __builtin_amdgcn_mfma_f32_16x16x32_bf16(cl0, bh0, acc, 0, 0, 0);  // lo.hi
    acc = __builtin_amdgcn_mfma_f32_16x16x32_bf16(cl1, bh1, acc, 0, 0, 0);

    float sq4[4] = {csq.x, csq.y, csq.z, csq.w};
#pragma unroll
    for (int reg = 0; reg < 4; ++reg) {
      float d = fmaf(-2.f, acc[reg], sq4[reg]);   // key: sq_j - 2 dot (sq_i dropped)
      unsigned k32 = __float_as_uint(d);
      k32 = ((int)k32 >= 0) ? (k32 | 0x80000000u) : ~k32;   // sortable map
      double key = fma((double)k32, 256.0, od + (double)reg);  // exact 40-bit int
      ins9(key, q9);
    }
    od += 4.0;
  }

  // f64 keys -> exact (k32, o) -> j -> packed u64; stage for in-wave quad merge
  unsigned long long q9u[9];
#pragma unroll
  for (int k = 0; k < 9; ++k) {
    double d  = q9[k];
    double hi = floor(d * 0.00390625);     // d * 2^-8, exact
    double lo = d - hi * 256.0;            // ordinal o, exact
    unsigned k32 = (unsigned)hi;
    int o = (int)lo;
    int j = cbase + (o >> 2) * 16 + quad * 4 + (o & 3);
    q9u[k] = ((unsigned long long)k32 << 14) | (unsigned)j;
    fin[wv][lane][k] = q9u[k];
  }
  __threadfence_block();
  if (lane < 16) {
    // stage 1: merge the wave's 4 quads -> per-wave list for query col=lane
#pragma unroll
    for (int qd = 1; qd < 4; ++qd) {
      const unsigned long long* ob = fin[wv][qd * 16 + lane];
      for (int k = 0; k < 9; ++k) {
        unsigned long long key = ob[k];
        if (key >= q9u[8]) break;          // sorted ascending
        unsigned long long cu = key;
#pragma unroll
        for (int kk = 0; kk < 9; ++kk) {
          bool lt = cu < q9u[kk];
          unsigned long long mn = lt ? cu : q9u[kk];
          cu      = lt ? q9u[kk] : cu;
          q9u[kk] = mn;
        }
      }
    }
    // restage per-wave merged list (only fin[wv][0..15] touched; own quad
    // reads above covered 16..63, other waves never read fin[wv])
#pragma unroll
    for (int k = 0; k < 9; ++k) fin[wv][lane][k] = q9u[k];
  }
  __syncthreads();
  // stage 2: wave 0 merges the 4 per-wave lists -> FINAL top-9; write nbr/deg
  if (wv == 0 && lane < 16) {
#pragma unroll
    for (int ow = 1; ow < 4; ++ow) {
      const unsigned long long* ob = fin[ow][lane];
      for (int k = 0; k < 9; ++k) {
        unsigned long long key = ob[k];
        if (key >= q9u[8]) break;          // sorted ascending
        unsigned long long cu = key;
#pragma unroll
        for (int kk = 0; kk < 9; ++kk) {
          bool lt = cu < q9u[kk];
          unsigned long long mn = lt ? cu : q9u[kk];
          cu      = lt ? q9u[kk] : cu;
          q9u[kk] = mn;
        }
      }
    }
    int i = qt * 16 + lane;
    int outi[9];
#pragma unroll
    for (int k = 0; k < 9; ++k) outi[k] = (int)(q9u[k] & 0x3FFFull);
    // node 16383 sits alone in "batch 4": top_k over one valid entry + (-inf)
    // ties -> neighbors {16383, 0,1,...,7} (lowest-index tie-break).
    if (i == NN - 1) {
      outi[0] = NN - 1;
#pragma unroll
      for (int k = 1; k < 9; ++k) outi[k] = k - 1;
    }
#pragma unroll
    for (int k = 0; k < 9; ++k) {
      nbr[i * 9 + k] = outi[k];
      atomicAdd(&deg[outi[k]], 1);
    }
  }
}

// ---------- kernel 3: tx1 gather + out = relu(xf@W0 + tx1@W1 + b) ----------
__global__ __launch_bounds__(256) void out_kernel(const float* __restrict__ xg,
                                                  const int* __restrict__ nbr,
                                                  const int* __restrict__ deg,
                                                  const float* __restrict__ W0,
                                                  const float* __restrict__ W1,
                                                  const float* __restrict__ bias,
                                                  float* __restrict__ out) {
  __shared__ float w0s[48 * 48], w1s[48 * 48], bsh[48];
  __shared__ __align__(16) float xr[64 * 48];
  __shared__ float tx[64 * 48];
  __shared__ float wd[64][9];
  __shared__ int   jn[64][9];
  __shared__ float din[64];
  int tid = threadIdx.x;
  int r0  = blockIdx.x * 64;

  for (int p = tid; p < 2304; p += 256) { w0s[p] = W0[p]; w1s[p] = W1[p]; }
  if (tid < 48) bsh[tid] = bias[tid];
  if (tid < 64) {
    int d = deg[r0 + tid];
    din[tid] = d > 0 ? rsqrtf((float)d) : 0.0f;
  }
  const float4* xg4 = (const float4*)xg;
  float4* xr4 = (float4*)xr;
  for (int p = tid; p < 768; p += 256) {
    int r = p / 12, q = p - r * 12;
    xr4[r * 12 + q] = xg4[(r0 + r) * 13 + q];
  }
  for (int p = tid; p < 576; p += 256) {
    int r = p / 9, k = p - r * 9;
    int j = nbr[(r0 + r) * 9 + k];
    jn[r][k] = j;
    int d = deg[j];
    wd[r][k] = d > 0 ? rsqrtf((float)d) : 0.0f;
  }
  __syncthreads();

  for (int p = tid; p < 3072; p += 256) {
    int r = p / 48, ch = p - r * 48;
    float s = 0.f;
#pragma unroll
    for (int k = 0; k < 9; ++k) s += wd[r][k] * xg[jn[r][k] * 52 + ch];
    tx[r * 48 + ch] = -din[r] * s;
  }
  __syncthreads();

  for (int p = tid; p < 3072; p += 256) {
    int r = p / 48, o = p - r * 48;
    float acc = bsh[o];
#pragma unroll
    for (int cc = 0; cc < 48; ++cc)
      acc += xr[r * 48 + cc] * w0s[cc * 48 + o] + tx[r * 48 + cc] * w1s[cc * 48 + o];
    out[(r0 + r) * 48 + o] = fmaxf(acc, 0.f);
  }
}

extern "C" void kernel_launch(void* const* d_in, const int* in_sizes, int n_in,
                              void* d_out, int out_size, void* d_ws, size_t ws_size,
                              hipStream_t stream) {
  const float* x  = (const float*)d_in[0];
  const float* W0 = (const float*)d_in[1];
  const float* W1 = (const float*)d_in[2];
  const float* b  = (const float*)d_in[3];
  float* out = (float*)d_out;
  char* ws = (char*)d_ws;
  float*          xg   = (float*)(ws);                       // 3,407,872 B
  unsigned short* xh   = (unsigned short*)(ws + 3407872);    // 2,097,152 B
  unsigned short* xl   = (unsigned short*)(ws + 5505024);    // 2,097,152 B
  float*          sqv  = (float*)(ws + 7602176);             //    65,536 B
  int*            nbr  = (int*)(ws + 7667712);               //   589,824 B
  int*            deg  = (int*)(ws + 8257536);               //    65,536 B

  prep_kernel<<<256, 256, 0, stream>>>(x, xg, xh, xl, sqv, deg);
  knn_kernel<<<1024, 256, 0, stream>>>(xh, xl, sqv, nbr, deg);
  out_kernel<<<256, 256, 0, stream>>>(xg, nbr, deg, W0, W1, b, out);
}

// Round 7
// 215.540 us; speedup vs baseline: 1.7708x; 1.0345x over previous
//
#include <hip/hip_runtime.h>

#define NN 16384   // total nodes (4*64*64)
#define CC 48      // channels

typedef __attribute__((ext_vector_type(8))) short bf16x8;
typedef __attribute__((ext_vector_type(4))) float f32x4;

__device__ __forceinline__ unsigned short f2bf(float f) {
  unsigned u = __float_as_uint(f);
  unsigned r = ((u >> 16) & 1u) + 0x7fffu;   // RNE
  return (unsigned short)((u + r) >> 16);
}
__device__ __forceinline__ float bf2f(unsigned short h) {
  return __uint_as_float(((unsigned)h) << 16);
}

// Parallel sorted-insert of key c into ascending q[0..8] (verified R0 form).
// Five rounds of measurement: this f64 network beats u32 value-only +
// recompute (R3/R4) and u32+payload cndmask (R5). Do not touch.
__device__ __forceinline__ void ins9(double c, double q[9]) {
  double m1 = fmin(q[1], c), m2 = fmin(q[2], c), m3 = fmin(q[3], c),
         m4 = fmin(q[4], c), m5 = fmin(q[5], c), m6 = fmin(q[6], c),
         m7 = fmin(q[7], c), m8 = fmin(q[8], c);
  double n0 = fmin(q[0], c);
  double n1 = fmax(q[0], m1), n2 = fmax(q[1], m2), n3 = fmax(q[2], m3),
         n4 = fmax(q[3], m4), n5 = fmax(q[4], m5), n6 = fmax(q[5], m6),
         n7 = fmax(q[6], m7), n8 = fmax(q[7], m8);
  q[0] = n0; q[1] = n1; q[2] = n2; q[3] = n3; q[4] = n4;
  q[5] = n5; q[6] = n6; q[7] = n7; q[8] = n8;
}

// ---------- kernel 1: [B,C,H,W] -> xg[N][52] fp32, xh/xl[N][64] bf16 split, sqv[N] ----------
// R7: vectorized both ends (G13): float4 x loads (tile pad 65->68 keeps 16B
// alignment; +4 banks/row stride is conflict-benign) and ushort4 xh/xl stores
// (4 contiguous channels per thread: 16 -> 4 store insts, coalesced).
// Also zeroes deg[]; sqv[16383] = +inf (excludes the lone "batch 4" node as a
// candidate at zero hot-loop cost).
__global__ __launch_bounds__(256) void prep_kernel(const float* __restrict__ x,
                                                   float* __restrict__ xg,
                                                   unsigned short* __restrict__ xh,
                                                   unsigned short* __restrict__ xl,
                                                   float* __restrict__ sqv,
                                                   int* __restrict__ deg) {
  __shared__ float tile[48][68];   // pad 68: float4-aligned rows (272 B)
  __shared__ float sqcol[64];
  int tid = threadIdx.x;
  int b   = blockIdx.x >> 6;          // batch image 0..3
  int hw0 = (blockIdx.x & 63) << 6;   // 64-wide hw tile
  if (tid < 64) deg[blockIdx.x * 64 + tid] = 0;
  const float4* x4 = (const float4*)x;
#pragma unroll
  for (int p = 0; p < 3; ++p) {
    int it = tid + p * 256;           // 768 float4 = 48 rows x 16
    int r = it >> 4, c4 = it & 15;
    float4 v = x4[(b * 48 + r) * 1024 + (hw0 >> 2) + c4];
    *(float4*)&tile[r][c4 * 4] = v;
  }
  __syncthreads();
  if (tid < 64) {
    float s = 0.f;
#pragma unroll
    for (int r = 0; r < 48; ++r) { float v = tile[r][tid]; s += v * v; }
    sqcol[tid] = s;
    int node = b * 4096 + hw0 + tid;
    sqv[node] = (node == NN - 1) ? __builtin_inff() : s;
  }
  __syncthreads();
  float4* xg4 = (float4*)xg;
#pragma unroll
  for (int p = 0; p < 4; ++p) {
    int it = tid + p * 256;
    if (it < 832) {
      int col = it / 13;
      int q   = it - col * 13;
      float4 v;
      if (q < 12) {
        v.x = tile[q * 4 + 0][col]; v.y = tile[q * 4 + 1][col];
        v.z = tile[q * 4 + 2][col]; v.w = tile[q * 4 + 3][col];
      } else {
        v.x = sqcol[col]; v.y = 0.f; v.z = 0.f; v.w = 0.f;
      }
      xg4[(b * 4096 + hw0 + col) * 13 + q] = v;
    }
  }
  // bf16 hi/lo split, channels padded 48..63 with zeros; ushort4 stores
#pragma unroll
  for (int p = 0; p < 4; ++p) {
    int it = tid + p * 256;          // 1024 = 64 nodes x 16 ch-quads
    int col = it >> 4, cq = it & 15, ch = cq * 4;
    ushort4 h4, l4;
    if (ch < 48) {
      float v0 = tile[ch + 0][col], v1 = tile[ch + 1][col],
            v2 = tile[ch + 2][col], v3 = tile[ch + 3][col];
      h4.x = f2bf(v0); h4.y = f2bf(v1); h4.z = f2bf(v2); h4.w = f2bf(v3);
      l4.x = f2bf(v0 - bf2f(h4.x)); l4.y = f2bf(v1 - bf2f(h4.y));
      l4.z = f2bf(v2 - bf2f(h4.z)); l4.w = f2bf(v3 - bf2f(h4.w));
    } else {
      h4.x = h4.y = h4.z = h4.w = 0;
      l4.x = l4.y = l4.z = l4.w = 0;
    }
    size_t o = (size_t)(b * 4096 + hw0 + col) * 64 + ch;
    *(ushort4*)(xh + o) = h4;
    *(ushort4*)(xl + o) = l4;
  }
}

// ---------- kernel 2: MFMA distance + exact f64 top-9, FUSED final merge ----------
// BYTE-IDENTICAL to the verified R6 kernel (148.5us). Block = one query-tile
// qt; 4 waves = 4 candidate quarters (64-tile streams); 2-stage LDS merge
// yields the FINAL top-9; writes nbr + atomicAdd deg directly.
__global__ __launch_bounds__(256, 4) void knn_kernel(const unsigned short* __restrict__ xh,
                                                     const unsigned short* __restrict__ xl,
                                                     const float* __restrict__ sqv,
                                                     int* __restrict__ nbr,
                                                     int* __restrict__ deg) {
  __shared__ unsigned long long fin[4][64][9];   // 18.4 KB, merge staging only
  int tid = threadIdx.x, wv = tid >> 6, lane = tid & 63;
  int qt = blockIdx.x;
  int col = lane & 15, quad = lane >> 4;
  int batch = qt >> 8;
  int cbase = batch * 4096 + wv * 1024;   // this wave's candidate quarter

  // resident B-frags (queries)
  int qnode = qt * 16 + col;
  bf16x8 bh0 = *(const bf16x8*)(xh + (size_t)qnode * 64 + quad * 8);
  bf16x8 bh1 = *(const bf16x8*)(xh + (size_t)qnode * 64 + 32 + quad * 8);
  bf16x8 bl0 = *(const bf16x8*)(xl + (size_t)qnode * 64 + quad * 8);
  bf16x8 bl1 = *(const bf16x8*)(xl + (size_t)qnode * 64 + 32 + quad * 8);

  double q9[9];
#pragma unroll
  for (int k = 0; k < 9; ++k) q9[k] = __builtin_inf();

  // prefetch tile 0: A-frags (candidate node cbase + col) + sq float4
  const unsigned short* pah = xh + ((size_t)(cbase + col) * 64 + quad * 8);
  const unsigned short* pal = xl + ((size_t)(cbase + col) * 64 + quad * 8);
  const float*          psq = sqv + (cbase + quad * 4);
  bf16x8 nh0 = *(const bf16x8*)(pah);
  bf16x8 nh1 = *(const bf16x8*)(pah + 32);
  bf16x8 nl0 = *(const bf16x8*)(pal);
  bf16x8 nl1 = *(const bf16x8*)(pal + 32);
  float4 nsq = *(const float4*)(psq);

  double od = 0.0;   // ordinal base = t*4 (exact integer in f64)
  for (int t = 0; t < 64; ++t) {
    bf16x8 ch0 = nh0, ch1 = nh1, cl0 = nl0, cl1 = nl1;
    float4 csq = nsq;
    int adv = (t < 63) ? 1024 : 0;       // 16 nodes * 64 ch
    pah += adv; pal += adv;
    nh0 = *(const bf16x8*)(pah);
    nh1 = *(const bf16x8*)(pah + 32);
    nl0 = *(const bf16x8*)(pal);
    nl1 = *(const bf16x8*)(pal + 32);
    psq += (t < 63) ? 16 : 0;
    nsq = *(const float4*)(psq);

    f32x4 acc = {0.f, 0.f, 0.f, 0.f};
    acc = __builtin_amdgcn_mfma_f32_16x16x32_bf16(ch0, bh0, acc, 0, 0, 0);  // hi.hi k0-31
    acc = __builtin_amdgcn_mfma_f32_16x16x32_bf16(ch1, bh1, acc, 0, 0, 0);  // hi.hi k32-63
    acc = __builtin_amdgcn_mfma_f32_16x16x32_bf16(ch0, bl0, acc, 0, 0, 0);  // hi.lo
    acc = __builtin_amdgcn_mfma_f32_16x16x32_bf16(ch1, bl1, acc, 0, 0, 0);
    acc = __builtin_amdgcn_mfma_f32_16x16x32_bf16(cl0, bh0, acc, 0, 0, 0);  // lo.hi
    acc = __builtin_amdgcn_mfma_f32_16x16x32_bf16(cl1, bh1, acc, 0, 0, 0);

    float sq4[4] = {csq.x, csq.y, csq.z, csq.w};
#pragma unroll
    for (int reg = 0; reg < 4; ++reg) {
      float d = fmaf(-2.f, acc[reg], sq4[reg]);   // key: sq_j - 2 dot (sq_i dropped)
      unsigned k32 = __float_as_uint(d);
      k32 = ((int)k32 >= 0) ? (k32 | 0x80000000u) : ~k32;   // sortable map
      double key = fma((double)k32, 256.0, od + (double)reg);  // exact 40-bit int
      ins9(key, q9);
    }
    od += 4.0;
  }

  // f64 keys -> exact (k32, o) -> j -> packed u64; stage for in-wave quad merge
  unsigned long long q9u[9];
#pragma unroll
  for (int k = 0; k < 9; ++k) {
    double d  = q9[k];
    double hi = floor(d * 0.00390625);     // d * 2^-8, exact
    double lo = d - hi * 256.0;            // ordinal o, exact
    unsigned k32 = (unsigned)hi;
    int o = (int)lo;
    int j = cbase + (o >> 2) * 16 + quad * 4 + (o & 3);
    q9u[k] = ((unsigned long long)k32 << 14) | (unsigned)j;
    fin[wv][lane][k] = q9u[k];
  }
  __threadfence_block();
  if (lane < 16) {
    // stage 1: merge the wave's 4 quads -> per-wave list for query col=lane
#pragma unroll
    for (int qd = 1; qd < 4; ++qd) {
      const unsigned long long* ob = fin[wv][qd * 16 + lane];
      for (int k = 0; k < 9; ++k) {
        unsigned long long key = ob[k];
        if (key >= q9u[8]) break;          // sorted ascending
        unsigned long long cu = key;
#pragma unroll
        for (int kk = 0; kk < 9; ++kk) {
          bool lt = cu < q9u[kk];
          unsigned long long mn = lt ? cu : q9u[kk];
          cu      = lt ? q9u[kk] : cu;
          q9u[kk] = mn;
        }
      }
    }
    // restage per-wave merged list (only fin[wv][0..15] touched; own quad
    // reads above covered 16..63, other waves never read fin[wv])
#pragma unroll
    for (int k = 0; k < 9; ++k) fin[wv][lane][k] = q9u[k];
  }
  __syncthreads();
  // stage 2: wave 0 merges the 4 per-wave lists -> FINAL top-9; write nbr/deg
  if (wv == 0 && lane < 16) {
#pragma unroll
    for (int ow = 1; ow < 4; ++ow) {
      const unsigned long long* ob = fin[ow][lane];
      for (int k = 0; k < 9; ++k) {
        unsigned long long key = ob[k];
        if (key >= q9u[8]) break;          // sorted ascending
        unsigned long long cu = key;
#pragma unroll
        for (int kk = 0; kk < 9; ++kk) {
          bool lt = cu < q9u[kk];
          unsigned long long mn = lt ? cu : q9u[kk];
          cu      = lt ? q9u[kk] : cu;
          q9u[kk] = mn;
        }
      }
    }
    int i = qt * 16 + lane;
    int outi[9];
#pragma unroll
    for (int k = 0; k < 9; ++k) outi[k] = (int)(q9u[k] & 0x3FFFull);
    // node 16383 sits alone in "batch 4": top_k over one valid entry + (-inf)
    // ties -> neighbors {16383, 0,1,...,7} (lowest-index tie-break).
    if (i == NN - 1) {
      outi[0] = NN - 1;
#pragma unroll
      for (int k = 1; k < 9; ++k) outi[k] = k - 1;
    }
#pragma unroll
    for (int k = 0; k < 9; ++k) {
      nbr[i * 9 + k] = outi[k];
      atomicAdd(&deg[outi[k]], 1);
    }
  }
}

// ---------- kernel 3: tx1 gather + out = relu(xf@W0 + tx1@W1 + b) ----------
// R7 restructure: 256 -> 1024 blocks (16 rows each). R6 ran 1 block/CU =
// 1 wave/SIMD — zero latency hiding for the 9-way scattered gather (~200cyc
// L2 hits) and the serial ds_read GEMM. Now LDS 26KB -> 4 blocks/CU resident
// (16 waves/CU). Weight staging is x4 redundant but L2-absorbed (~19MB).
// Inner logic identical, only the row-tile size changed.
__global__ __launch_bounds__(256) void out_kernel(const float* __restrict__ xg,
                                                  const int* __restrict__ nbr,
                                                  const int* __restrict__ deg,
                                                  const float* __restrict__ W0,
                                                  const float* __restrict__ W1,
                                                  const float* __restrict__ bias,
                                                  float* __restrict__ out) {
  __shared__ float w0s[48 * 48], w1s[48 * 48], bsh[48];
  __shared__ __align__(16) float xr[16 * 48];
  __shared__ float tx[16 * 48];
  __shared__ float wd[16][9];
  __shared__ int   jn[16][9];
  __shared__ float din[16];
  int tid = threadIdx.x;
  int r0  = blockIdx.x * 16;

  // weight staging, vectorized: 2304 floats = 576 float4 per matrix
  const float4* W04 = (const float4*)W0;
  const float4* W14 = (const float4*)W1;
  float4* w0s4 = (float4*)w0s;
  float4* w1s4 = (float4*)w1s;
  for (int p = tid; p < 576; p += 256) { w0s4[p] = W04[p]; w1s4[p] = W14[p]; }
  if (tid < 48) bsh[tid] = bias[tid];
  if (tid < 16) {
    int d = deg[r0 + tid];
    din[tid] = d > 0 ? rsqrtf((float)d) : 0.0f;
  }
  const float4* xg4 = (const float4*)xg;
  float4* xr4 = (float4*)xr;
  if (tid < 192) {                      // 16 rows x 12 float4
    int r = tid / 12, q = tid - r * 12;
    xr4[r * 12 + q] = xg4[(r0 + r) * 13 + q];
  }
  if (tid < 144) {                      // 16 rows x 9 neighbors
    int r = tid / 9, k = tid - r * 9;
    int j = nbr[(r0 + r) * 9 + k];
    jn[r][k] = j;
    int d = deg[j];
    wd[r][k] = d > 0 ? rsqrtf((float)d) : 0.0f;
  }
  __syncthreads();

  for (int p = tid; p < 768; p += 256) {   // 16 rows x 48 ch
    int r = p / 48, ch = p - r * 48;
    float s = 0.f;
#pragma unroll
    for (int k = 0; k < 9; ++k) s += wd[r][k] * xg[jn[r][k] * 52 + ch];
    tx[r * 48 + ch] = -din[r] * s;
  }
  __syncthreads();

  for (int p = tid; p < 768; p += 256) {   // 16 rows x 48 outs
    int r = p / 48, o = p - r * 48;
    float acc = bsh[o];
#pragma unroll
    for (int cc = 0; cc < 48; ++cc)
      acc += xr[r * 48 + cc] * w0s[cc * 48 + o] + tx[r * 48 + cc] * w1s[cc * 48 + o];
    out[(r0 + r) * 48 + o] = fmaxf(acc, 0.f);
  }
}

extern "C" void kernel_launch(void* const* d_in, const int* in_sizes, int n_in,
                              void* d_out, int out_size, void* d_ws, size_t ws_size,
                              hipStream_t stream) {
  const float* x  = (const float*)d_in[0];
  const float* W0 = (const float*)d_in[1];
  const float* W1 = (const float*)d_in[2];
  const float* b  = (const float*)d_in[3];
  float* out = (float*)d_out;
  char* ws = (char*)d_ws;
  float*          xg   = (float*)(ws);                       // 3,407,872 B
  unsigned short* xh   = (unsigned short*)(ws + 3407872);    // 2,097,152 B
  unsigned short* xl   = (unsigned short*)(ws + 5505024);    // 2,097,152 B
  float*          sqv  = (float*)(ws + 7602176);             //    65,536 B
  int*            nbr  = (int*)(ws + 7667712);               //   589,824 B
  int*            deg  = (int*)(ws + 8257536);               //    65,536 B

  prep_kernel<<<256, 256, 0, stream>>>(x, xg, xh, xl, sqv, deg);
  knn_kernel<<<1024, 256, 0, stream>>>(xh, xl, sqv, nbr, deg);
  out_kernel<<<1024, 256, 0, stream>>>(xg, nbr, deg, W0, W1, b, out);
}